// Round 2
// baseline (396.946 us; speedup 1.0000x reference)
//
#include <hip/hip_runtime.h>
#include <hip/hip_bf16.h>
#include <cstdint>
#include <cstddef>

typedef __bf16 bf16x8 __attribute__((ext_vector_type(8)));
typedef float floatx4 __attribute__((ext_vector_type(4)));

#define NROIS 1000
#define PD    12544   // 256*49
#define K2_1  25088   // 2*PD  (hi/lo interleaved)
#define FC_N  1024
#define K2_2  2048    // 2*1024
#define NLOC  324
#define NSC   81
#define NH    405

// ---- workspace layout (float offsets) -------------------------------------
#define OFF_FT   0u          // fT: 22,282,240 floats (89.1 MB), dead after roi_pool
#define OFF_W1T  0u          // aliases fT: 1024*25088 bf16 = 12,845,056 floats
#define OFF_PART 12845056u   // 8*1024*1024 fp32 = 8,388,608 floats (in fT region)
#define OFF_T2   0u
#define OFF_T3   16777216u
#define OFF_T4   20971520u
#define OFF_T5   22020096u
#define OFF_POOL 22282240u   // pooled_hl: 1024*25088 bf16 = 12,845,056 floats
#define OFF_W2T  35127296u   // 1024*2048 bf16 = 1,048,576 floats
#define OFF_WHT  36175872u   // 512*2048 bf16  =   524,288 floats
#define OFF_FC1  36700160u   // 1024*2048 bf16 = 1,048,576 floats
#define OFF_FC2  37748736u   // end = 38,797,312 floats (155.2 MB)

// ---- bf16 hi/lo helpers ----------------------------------------------------
__device__ __forceinline__ unsigned short f2bf(float x) {
    unsigned int u = __float_as_uint(x);
    u = u + 0x7fffu + ((u >> 16) & 1u);          // RNE
    return (unsigned short)(u >> 16);
}
__device__ __forceinline__ float bf2f(unsigned short h) {
    return __uint_as_float(((unsigned int)h) << 16);
}
__device__ __forceinline__ ushort2 split_hl(float f) {
    const unsigned short hi = f2bf(f);
    const unsigned short lo = f2bf(f - bf2f(hi));
    return make_ushort2(hi, lo);
}

// ---------------------------------------------------------------------------
// Fused transpose of all 4 pyramid levels [256][P] -> [P][256] fp32.
// ---------------------------------------------------------------------------
__global__ __launch_bounds__(256) void transpose_feat_kernel(
    const float* __restrict__ f2, const float* __restrict__ f3,
    const float* __restrict__ f4, const float* __restrict__ f5,
    float* __restrict__ fT)
{
    __shared__ float tile[64][65];
    int bx = blockIdx.x;
    const float* src; float* dst; int P;
    if (bx < 1024)      {            src = f2; dst = fT + OFF_T2; P = 65536; }
    else if (bx < 1280) { bx -= 1024; src = f3; dst = fT + OFF_T3; P = 16384; }
    else if (bx < 1344) { bx -= 1280; src = f4; dst = fT + OFF_T4; P = 4096; }
    else                { bx -= 1344; src = f5; dst = fT + OFF_T5; P = 1024; }

    const int p0  = bx * 64;
    const int c0  = blockIdx.y * 64;
    const int col = threadIdx.x & 63;
    const int r0  = threadIdx.x >> 6;
#pragma unroll
    for (int r = r0; r < 64; r += 4)
        tile[r][col] = src[(size_t)(c0 + r) * P + p0 + col];
    __syncthreads();
#pragma unroll
    for (int r = r0; r < 64; r += 4)
        dst[(size_t)(p0 + r) * 256 + c0 + col] = tile[col][r];
}

// ---------------------------------------------------------------------------
// ROI align + 2x2 max.
// Block = (roi, ph), 256 threads:
//   lane (0..63)  = float4 channel group (channels 4*lane .. 4*lane+3)
//   wave (0..3)   = (syy = wave>>1, sx parity = wave&1)
// Each wave computes its 7 bilinear samples (one per pw) as float4; the 2x2
// max is a 4-way LDS combine. Same arithmetic as before (fmax reorder is
// exact), but 4x fewer memory instructions (64 lanes x 16B = 1KB/instr) and
// a 7-long instead of 28-long dependent chain.
// Output: interleaved hi/lo bf16 [roi][cell*256+c].
// ---------------------------------------------------------------------------
__global__ __launch_bounds__(256) void roi_pool_kernel(
    const float* __restrict__ fT, const float* __restrict__ rois,
    const int* __restrict__ img_size, ushort2* __restrict__ pooledHL)
{
    const int roi  = blockIdx.x;        // 0..999
    const int ph   = blockIdx.y;        // 0..6
    const int tid  = threadIdx.x;
    const int lane = tid & 63;
    const int wave = tid >> 6;
    const int syy  = wave >> 1;
    const int sxp  = wave & 1;

    const float y1 = rois[roi * 4 + 0];
    const float x1 = rois[roi * 4 + 1];
    const float y2 = rois[roi * 4 + 2];
    const float x2 = rois[roi * 4 + 3];

    const float hh = y2 - y1 + 1.0f;
    const float ww = x2 - x1 + 1.0f;
    float lvlf = floorf(logf(sqrtf(hh * ww) / 224.0f) / 0.693147f + 4.0f);
    lvlf = fminf(fmaxf(lvlf, 2.0f), 5.0f);
    const int lvl = (int)lvlf;

    const float* f;
    int H;
    if (lvl == 2)      { f = fT + OFF_T2; H = 256; }
    else if (lvl == 3) { f = fT + OFF_T3; H = 128; }
    else if (lvl == 4) { f = fT + OFF_T4; H = 64;  }
    else               { f = fT + OFF_T5; H = 32;  }
    const int W = H;

    const float imh = (float)img_size[0] - 1.0f;
    const float imw = (float)img_size[1] - 1.0f;
    const float r0 = y1 * (float)(H - 1) / imh;
    const float r1 = x1 * (float)(W - 1) / imw;
    const float r2 = y2 * (float)(H - 1) / imh;
    const float r3 = x2 * (float)(W - 1) / imw;
    const float hs  = (r2 - r0) * (1.0f / 14.0f);
    const float wst = (r3 - r1) * (1.0f / 14.0f);

    // row pair for this wave's syy (constant across pw)
    const float cy = ((float)(ph * 2 + syy) + 0.5f) * hs + r0;
    const float fy = floorf(cy);
    int   iu  = (int)fy;
    int   idn = (int)ceilf(cy);
    const float ly = cy - fy;
    iu  = min(max(iu, 0),  H - 1);
    idn = min(max(idn, 0), H - 1);
    const float wU = 1.0f - ly, wD = ly;
    const float4* rowU = (const float4*)(f + (size_t)(iu  * W) * 256);
    const float4* rowD = (const float4*)(f + (size_t)(idn * W) * 256);

    __shared__ float4 red[4][7][64];    // 28 KB

#pragma unroll
    for (int pw = 0; pw < 7; ++pw) {
        const int sx = pw * 2 + sxp;
        const float cx = ((float)sx + 0.5f) * wst + r1;
        const float fx = floorf(cx);
        int   il = (int)fx;
        int   ir = (int)ceilf(cx);
        const float lx = cx - fx;
        il = min(max(il, 0), W - 1);
        ir = min(max(ir, 0), W - 1);

        const float4 v00 = rowU[il * 64 + lane];
        const float4 v01 = rowU[ir * 64 + lane];
        const float4 v10 = rowD[il * 64 + lane];
        const float4 v11 = rowD[ir * 64 + lane];
        const float lxm = 1.0f - lx;
        float4 v;
        v.x = (v00.x * lxm + v01.x * lx) * wU + (v10.x * lxm + v11.x * lx) * wD;
        v.y = (v00.y * lxm + v01.y * lx) * wU + (v10.y * lxm + v11.y * lx) * wD;
        v.z = (v00.z * lxm + v01.z * lx) * wU + (v10.z * lxm + v11.z * lx) * wD;
        v.w = (v00.w * lxm + v01.w * lx) * wU + (v10.w * lxm + v11.w * lx) * wD;
        red[wave][pw][lane] = v;
    }
    __syncthreads();

    // 4-way max combine + hi/lo split store: 7*64 = 448 float4 outputs
    for (int idx = tid; idx < 448; idx += 256) {
        const int pw = idx >> 6, cg = idx & 63;
        const float4 a = red[0][pw][cg];
        const float4 b = red[1][pw][cg];
        const float4 c = red[2][pw][cg];
        const float4 d = red[3][pw][cg];
        float4 mv;
        mv.x = fmaxf(fmaxf(a.x, b.x), fmaxf(c.x, d.x));
        mv.y = fmaxf(fmaxf(a.y, b.y), fmaxf(c.y, d.y));
        mv.z = fmaxf(fmaxf(a.z, b.z), fmaxf(c.z, d.z));
        mv.w = fmaxf(fmaxf(a.w, b.w), fmaxf(c.w, d.w));
        union { ushort2 u2[4]; uint4 v4; } pk;
        pk.u2[0] = split_hl(mv.x);
        pk.u2[1] = split_hl(mv.y);
        pk.u2[2] = split_hl(mv.z);
        pk.u2[3] = split_hl(mv.w);
        ushort2* outp = pooledHL + (size_t)roi * PD + (ph * 7 + pw) * 256 + cg * 4;
        *reinterpret_cast<uint4*>(outp) = pk.v4;
    }
}

// ---------------------------------------------------------------------------
// W1 [12544][1024] fp32 -> W1T [1024 rows][25088] bf16 (transposed, hi/lo
// interleaved, GEMM1 k-permutation folded).
// ---------------------------------------------------------------------------
__global__ __launch_bounds__(256) void convert_w1_kernel(
    const float* __restrict__ W1, ushort2* __restrict__ W1T)
{
    __shared__ float tile[64][65];
    const int p0  = blockIdx.x * 64;
    const int n0  = blockIdx.y * 64;
    const int col = threadIdx.x & 63;
    const int r0  = threadIdx.x >> 6;
#pragma unroll
    for (int r = r0; r < 64; r += 4) {
        const int pp   = p0 + r;
        const int ksrc = (pp & 255) * 49 + (pp >> 8);
        tile[r][col] = W1[(size_t)ksrc * 1024 + n0 + col];
    }
    __syncthreads();
#pragma unroll
    for (int nr = r0; nr < 64; nr += 4)
        W1T[(size_t)(n0 + nr) * PD + p0 + col] = split_hl(tile[col][nr]);
}

// ---------------------------------------------------------------------------
// Merged: W2 -> W2T [1024][2048] (grid.y<16) and [Wloc|Wsc] -> WhT [512][2048]
// ---------------------------------------------------------------------------
__global__ __launch_bounds__(256) void convert_w2h_kernel(
    const float* __restrict__ W2, const float* __restrict__ Wloc,
    const float* __restrict__ Wsc, ushort2* __restrict__ W2T,
    ushort2* __restrict__ WhT)
{
    __shared__ float tile[64][65];
    const int p0  = blockIdx.x * 64;
    const int col = threadIdx.x & 63;
    const int r0  = threadIdx.x >> 6;

    if (blockIdx.y < 16) {
        const int n0 = blockIdx.y * 64;
#pragma unroll
        for (int r = r0; r < 64; r += 4)
            tile[r][col] = W2[(size_t)(p0 + r) * 1024 + n0 + col];
        __syncthreads();
#pragma unroll
        for (int nr = r0; nr < 64; nr += 4)
            W2T[(size_t)(n0 + nr) * 1024 + p0 + col] = split_hl(tile[col][nr]);
    } else {
        const int n0 = (blockIdx.y - 16) * 64;
#pragma unroll
        for (int r = r0; r < 64; r += 4) {
            const int pp = p0 + r;
            const int n  = n0 + col;
            float v = 0.0f;
            if (n < NLOC)    v = Wloc[(size_t)pp * NLOC + n];
            else if (n < NH) v = Wsc[(size_t)pp * NSC + (n - NLOC)];
            tile[r][col] = v;
        }
        __syncthreads();
#pragma unroll
        for (int nr = r0; nr < 64; nr += 4)
            WhT[(size_t)(n0 + nr) * 1024 + p0 + col] = split_hl(tile[col][nr]);
    }
}

// ---------------------------------------------------------------------------
// bf16 MFMA GEMM v3: tile 128(M)x128(N), BK=64, 4 waves (2x2), each wave owns
// a 64x64 sub-tile (acc[4][4] of 16x16 frags). global_load_lds width 16 with
// XOR-swizzled LDS (linear dest + pre-swizzled global source, read-side XOR).
// grid = (splitK, N/128, M/128). 32 KB LDS.
// partial[z][m][n], z-stride = (gridDim.z*128)*N.
// ---------------------------------------------------------------------------
__global__ __launch_bounds__(256) void gemm_bf16_kernel(
    const unsigned short* __restrict__ A,
    const unsigned short* __restrict__ B,
    float* __restrict__ partial,
    int K2, int N, int kLen)
{
    __shared__ __align__(16) unsigned short As[128 * 64];   // 16 KB
    __shared__ __align__(16) unsigned short Bs[128 * 64];   // 16 KB

    const int tid  = threadIdx.x;
    const int lane = tid & 63;
    const int wave = tid >> 6;
    const int kStart = blockIdx.x * kLen;
    const int n0 = blockIdx.y * 128;
    const int m0 = blockIdx.z * 128;

    const int wr = wave >> 1;            // wave row (0..1) -> M offset wr*64
    const int wc = wave & 1;             // wave col (0..1) -> N offset wc*64

    const int rIn  = lane >> 3;          // 0..7 (row within 8-row stripe)
    const int cSrc = (lane & 7) ^ rIn;   // XOR-swizzled source chunk

    const int mrow = lane & 15, quad = lane >> 4;

    floatx4 acc[4][4];
#pragma unroll
    for (int mi = 0; mi < 4; ++mi)
#pragma unroll
        for (int nj = 0; nj < 4; ++nj)
            acc[mi][nj] = (floatx4){0.f, 0.f, 0.f, 0.f};

    for (int k0 = kStart; k0 < kStart + kLen; k0 += 64) {
        // stage A: wave w -> rows [w*32, w*32+32)
#pragma unroll
        for (int q = 0; q < 4; ++q) {
            const int rowBase = wave * 32 + q * 8;
            const unsigned short* ga =
                A + (size_t)(m0 + rowBase + rIn) * K2 + k0 + cSrc * 8;
            __builtin_amdgcn_global_load_lds(
                (const __attribute__((address_space(1))) void*)ga,
                (__attribute__((address_space(3))) void*)&As[rowBase * 64], 16, 0, 0);
        }
        // stage B: wave w -> rows [w*32, w*32+32)
#pragma unroll
        for (int q = 0; q < 4; ++q) {
            const int rowBase = wave * 32 + q * 8;
            const unsigned short* gb =
                B + (size_t)(n0 + rowBase + rIn) * K2 + k0 + cSrc * 8;
            __builtin_amdgcn_global_load_lds(
                (const __attribute__((address_space(1))) void*)gb,
                (__attribute__((address_space(3))) void*)&Bs[rowBase * 64], 16, 0, 0);
        }
        __syncthreads();

#pragma unroll
        for (int ks = 0; ks < 2; ++ks) {
            const int chunk = ks * 4 + quad;
            bf16x8 aF[4], bF[4];
#pragma unroll
            for (int mi = 0; mi < 4; ++mi) {
                const int ra = wr * 64 + mi * 16 + mrow;
                aF[mi] = *reinterpret_cast<const bf16x8*>(
                    &As[ra * 64 + ((chunk ^ (ra & 7)) * 8)]);
            }
#pragma unroll
            for (int nj = 0; nj < 4; ++nj) {
                const int rb = wc * 64 + nj * 16 + mrow;
                bF[nj] = *reinterpret_cast<const bf16x8*>(
                    &Bs[rb * 64 + ((chunk ^ (rb & 7)) * 8)]);
            }
#pragma unroll
            for (int mi = 0; mi < 4; ++mi)
#pragma unroll
                for (int nj = 0; nj < 4; ++nj)
                    acc[mi][nj] = __builtin_amdgcn_mfma_f32_16x16x32_bf16(
                        aF[mi], bF[nj], acc[mi][nj], 0, 0, 0);
        }
        __syncthreads();
    }

    // C/D layout: col = lane&15, row = quad*4 + reg
    float* p = partial + (size_t)blockIdx.x * (size_t)(gridDim.z * 128) * N;
#pragma unroll
    for (int mi = 0; mi < 4; ++mi) {
        const int row = m0 + wr * 64 + mi * 16 + quad * 4;
#pragma unroll
        for (int nj = 0; nj < 4; ++nj) {
            const int col = n0 + wc * 64 + nj * 16 + mrow;
#pragma unroll
            for (int r = 0; r < 4; ++r)
                p[(size_t)(row + r) * N + col] = acc[mi][nj][r];
        }
    }
}

// ---------------------------------------------------------------------------
// fc = relu(sum_z partial + bias) -> hi/lo bf16 interleaved. float4 path.
// ---------------------------------------------------------------------------
__global__ __launch_bounds__(256) void reduce_fc_kernel(
    const float* __restrict__ partial, const float* __restrict__ bias,
    ushort2* __restrict__ outHL, int nz)
{
    const int i4 = blockIdx.x * 256 + threadIdx.x;
    const int off = i4 * 4;
    const int m = off >> 10, n = off & 1023;
    float4 acc = *reinterpret_cast<const float4*>(partial + off);
    for (int z = 1; z < nz; ++z) {
        const float4 v = *reinterpret_cast<const float4*>(
            partial + (size_t)z * 1024 * 1024 + off);
        acc.x += v.x; acc.y += v.y; acc.z += v.z; acc.w += v.w;
    }
    const float4 bv = *reinterpret_cast<const float4*>(bias + n);
    ushort2* o = outHL + (size_t)m * 1024 + n;
    o[0] = split_hl(fmaxf(acc.x + bv.x, 0.f));
    o[1] = split_hl(fmaxf(acc.y + bv.y, 0.f));
    o[2] = split_hl(fmaxf(acc.z + bv.z, 0.f));
    o[3] = split_hl(fmaxf(acc.w + bv.w, 0.f));
}

// heads: sum partials [z][1024][512], add bias, split-store to out0/out1
__global__ __launch_bounds__(256) void reduce_heads_kernel(
    const float* __restrict__ partial, const float* __restrict__ bloc,
    const float* __restrict__ bsc, float* __restrict__ out0,
    float* __restrict__ out1, int nz)
{
    const int m = blockIdx.x;   // 0..999
    for (int n = threadIdx.x; n < NH; n += 256) {
        float s = 0.f;
        for (int z = 0; z < nz; ++z)
            s += partial[(size_t)z * 1024 * 512 + (size_t)m * 512 + n];
        if (n < NLOC) out0[(size_t)m * NLOC + n] = s + bloc[n];
        else          out1[(size_t)m * NSC + (n - NLOC)] = s + bsc[n - NLOC];
    }
}

// ---------------------------------------------------------------------------
extern "C" void kernel_launch(void* const* d_in, const int* in_sizes, int n_in,
                              void* d_out, int out_size, void* d_ws, size_t ws_size,
                              hipStream_t stream)
{
    const float* f2   = (const float*)d_in[0];
    const float* f3   = (const float*)d_in[1];
    const float* f4   = (const float*)d_in[2];
    const float* f5   = (const float*)d_in[3];
    const float* rois = (const float*)d_in[4];
    const int*   img  = (const int*)d_in[5];
    const float* W1   = (const float*)d_in[6];
    const float* b1   = (const float*)d_in[7];
    const float* W2   = (const float*)d_in[8];
    const float* b2   = (const float*)d_in[9];
    const float* Wloc = (const float*)d_in[10];
    const float* bloc = (const float*)d_in[11];
    const float* Wsc  = (const float*)d_in[12];
    const float* bsc  = (const float*)d_in[13];
    float* out = (float*)d_out;

    float* ws = (float*)d_ws;
    float*   fT     = ws + OFF_FT;
    ushort2* pooled = (ushort2*)(ws + OFF_POOL);
    ushort2* w1t    = (ushort2*)(ws + OFF_W1T);     // aliases fT (dead then)
    float*   part   = ws + OFF_PART;                // aliases fT tail
    ushort2* w2t    = (ushort2*)(ws + OFF_W2T);
    ushort2* wht    = (ushort2*)(ws + OFF_WHT);
    ushort2* fc1    = (ushort2*)(ws + OFF_FC1);
    ushort2* fc2    = (ushort2*)(ws + OFF_FC2);

    // 1) feature transpose to [pix][256], all levels fused
    transpose_feat_kernel<<<dim3(1360, 4), 256, 0, stream>>>(f2, f3, f4, f5, fT);

    // 2) ROI pool, block per (roi, ph)
    roi_pool_kernel<<<dim3(NROIS, 7), 256, 0, stream>>>(fT, rois, img, pooled);

    // 3) weight conversions (W1T aliases fT region, dead after roi_pool)
    convert_w1_kernel<<<dim3(196, 16), 256, 0, stream>>>(W1, w1t);
    convert_w2h_kernel<<<dim3(16, 23), 256, 0, stream>>>(W2, Wloc, Wsc, w2t, wht);

    // 4) fc1 = relu(pooled @ W1 + b1): grid (k=8, n=8, m=8) = 512 blocks
    gemm_bf16_kernel<<<dim3(8, 8, 8), 256, 0, stream>>>(
        (const unsigned short*)pooled, (const unsigned short*)w1t, part,
        K2_1, 1024, K2_1 / 8);
    reduce_fc_kernel<<<1024, 256, 0, stream>>>(part, b1, fc1, 8);

    // 5) fc2 = relu(fc1 @ W2 + b2): grid (k=8, n=8, m=8) = 512 blocks
    gemm_bf16_kernel<<<dim3(8, 8, 8), 256, 0, stream>>>(
        (const unsigned short*)fc1, (const unsigned short*)w2t, part,
        K2_2, 1024, K2_2 / 8);
    reduce_fc_kernel<<<1024, 256, 0, stream>>>(part, b2, fc2, 8);

    // 6) heads: N=512, grid (k=8, n=4, m=8) = 256 blocks
    gemm_bf16_kernel<<<dim3(8, 4, 8), 256, 0, stream>>>(
        (const unsigned short*)fc2, (const unsigned short*)wht, part,
        K2_2, 512, K2_2 / 8);
    reduce_heads_kernel<<<NROIS, 256, 0, stream>>>(
        part, bloc, bsc, out, out + (size_t)NROIS * NLOC, 8);
}